// Round 1
// baseline (1185.575 us; speedup 1.0000x reference)
//
#include <hip/hip_runtime.h>
#include <math.h>

#define UNITS 64
#define TT 100
#define NB 32          // batch elements per workgroup
#define NTH 256        // threads per workgroup (4 waves)
#define CREG (NB*UNITS/NTH)   // 8 c-state registers per thread

__device__ __forceinline__ float rcp_fast(float x) { return __builtin_amdgcn_rcpf(x); }

__device__ __forceinline__ float fast_sigmoid(float x) {
    // 1/(1+exp(-x)); x<<0 -> e=inf -> rcp(inf)=0; x>>0 -> e=0 -> 1.  Safe.
    float e = __expf(-x);
    return rcp_fast(1.0f + e);
}

__device__ __forceinline__ float fast_tanh(float x) {
    // tanh via exp of -2|x| (e<=1, no overflow), restore sign.
    float ax = fabsf(x);
    float e = __expf(-2.0f * ax);
    float t = (1.0f - e) * rcp_fast(1.0f + e);
    return copysignf(t, x);
}

__global__ __launch_bounds__(NTH) void lstm_fused_kernel(
    const float* __restrict__ x,    // (B, 100, 3)
    const float* __restrict__ W,    // (3, 256)
    const float* __restrict__ U,    // (64, 256)
    const float* __restrict__ bias, // (256,)
    const float* __restrict__ W1,   // (64, 64)
    const float* __restrict__ b1,   // (64,)
    const float* __restrict__ W2,   // (64, 5)
    const float* __restrict__ b2,   // (5,)
    float* __restrict__ out)        // (B, 5)
{
    __shared__ float hbuf[NB * UNITS];      // 8 KB   h state
    __shared__ float zbuf[NB * 4 * UNITS];  // 32 KB  activated gates; reused as h1
    __shared__ float xbuf[NB * 3];
    __shared__ float maskbuf[NB];
    __shared__ float logitbuf[NB * 5];

    const int tid = threadIdx.x;
    const int b0  = blockIdx.x * NB;

    // Per-thread column of U (64 VGPRs), W column (3), bias (1).
    float u[UNITS];
    #pragma unroll
    for (int k = 0; k < UNITS; ++k) u[k] = U[k * 256 + tid];
    const float w0 = W[tid], w1 = W[256 + tid], w2 = W[512 + tid];
    const float bz = bias[tid];

    // c state: thread owns components comp = r*256 + tid, r = 0..7
    float c[CREG];
    #pragma unroll
    for (int r = 0; r < CREG; ++r) c[r] = 0.0f;
    #pragma unroll
    for (int r = 0; r < CREG; ++r) hbuf[r * NTH + tid] = 0.0f;

    const int gate = tid >> 6;  // 0=i 1=f 2=g 3=o  (wave-uniform)

    #pragma unroll 1
    for (int t = 0; t < TT; ++t) {
        __syncthreads();  // state writes (prev iter) / xbuf reads (prev iter) done
        if (tid < NB) {
            const int gb = b0 + tid;
            const float x0 = x[gb * (TT * 3) + t * 3 + 0];
            const float x1 = x[gb * (TT * 3) + t * 3 + 1];
            const float x2 = x[gb * (TT * 3) + t * 3 + 2];
            xbuf[tid * 3 + 0] = x0;
            xbuf[tid * 3 + 1] = x1;
            xbuf[tid * 3 + 2] = x2;
            maskbuf[tid] = (x0 != 0.0f || x1 != 0.0f || x2 != 0.0f) ? 1.0f : 0.0f;
        }
        __syncthreads();

        // z stage: thread tid computes activated gate column tid for each b
        #pragma unroll 2
        for (int b = 0; b < NB; ++b) {
            if (maskbuf[b] != 0.0f) {           // wave-uniform skip of dead steps
                float acc = bz + xbuf[b * 3 + 0] * w0
                               + xbuf[b * 3 + 1] * w1
                               + xbuf[b * 3 + 2] * w2;
                const float4* hp = (const float4*)(hbuf + b * UNITS);  // broadcast reads
                #pragma unroll
                for (int kk = 0; kk < UNITS / 4; ++kk) {
                    const float4 hv = hp[kk];
                    acc += hv.x * u[4 * kk + 0];
                    acc += hv.y * u[4 * kk + 1];
                    acc += hv.z * u[4 * kk + 2];
                    acc += hv.w * u[4 * kk + 3];
                }
                zbuf[b * 256 + tid] = (gate == 2) ? fast_tanh(acc) : fast_sigmoid(acc);
            }
        }
        __syncthreads();

        // update stage: comp = r*256+tid -> b = comp/64 (wave-uniform), k = comp%64
        #pragma unroll
        for (int r = 0; r < CREG; ++r) {
            const int comp = r * NTH + tid;
            const int b = comp >> 6;
            const int k = comp & 63;
            if (maskbuf[b] != 0.0f) {
                const float iv = zbuf[b * 256 +   0 + k];
                const float fv = zbuf[b * 256 +  64 + k];
                const float gv = zbuf[b * 256 + 128 + k];
                const float ov = zbuf[b * 256 + 192 + k];
                const float cn = fv * c[r] + iv * gv;
                c[r] = cn;
                hbuf[b * UNITS + k] = ov * fast_tanh(cn);
            }
        }
    }
    __syncthreads();

    // ---- epilogue: h1 = relu(h @ W1 + b1) into zbuf ----
    {
        const int j  = tid & 63;
        const int bb = tid >> 6;  // 0..3
        const float bj = b1[j];
        for (int p = 0; p < NB / 4; ++p) {
            const int b = p * 4 + bb;
            float acc = bj;
            #pragma unroll 8
            for (int k = 0; k < UNITS; ++k)
                acc += hbuf[b * UNITS + k] * W1[k * 64 + j];   // hbuf broadcast, W1 coalesced
            zbuf[b * 64 + j] = fmaxf(acc, 0.0f);
        }
    }
    __syncthreads();

    // ---- logits = h1 @ W2 + b2 ----
    if (tid < NB * 5) {
        const int b = tid / 5, s = tid % 5;
        float acc = b2[s];
        for (int j = 0; j < 64; ++j)
            acc += zbuf[b * 64 + j] * W2[j * 5 + s];
        logitbuf[b * 5 + s] = acc;
    }
    __syncthreads();

    // ---- softmax over 5, write out ----
    if (tid < NB) {
        const float l0 = logitbuf[tid * 5 + 0];
        const float l1 = logitbuf[tid * 5 + 1];
        const float l2 = logitbuf[tid * 5 + 2];
        const float l3 = logitbuf[tid * 5 + 3];
        const float l4 = logitbuf[tid * 5 + 4];
        const float m  = fmaxf(fmaxf(fmaxf(l0, l1), fmaxf(l2, l3)), l4);
        const float e0 = __expf(l0 - m), e1 = __expf(l1 - m), e2 = __expf(l2 - m);
        const float e3 = __expf(l3 - m), e4 = __expf(l4 - m);
        const float rs = 1.0f / (e0 + e1 + e2 + e3 + e4);
        const int gb = b0 + tid;
        out[gb * 5 + 0] = e0 * rs;
        out[gb * 5 + 1] = e1 * rs;
        out[gb * 5 + 2] = e2 * rs;
        out[gb * 5 + 3] = e3 * rs;
        out[gb * 5 + 4] = e4 * rs;
    }
}

extern "C" void kernel_launch(void* const* d_in, const int* in_sizes, int n_in,
                              void* d_out, int out_size, void* d_ws, size_t ws_size,
                              hipStream_t stream) {
    const float* x  = (const float*)d_in[0];
    const float* W  = (const float*)d_in[1];
    const float* U  = (const float*)d_in[2];
    const float* b  = (const float*)d_in[3];
    const float* W1 = (const float*)d_in[4];
    const float* b1 = (const float*)d_in[5];
    const float* W2 = (const float*)d_in[6];
    const float* b2 = (const float*)d_in[7];
    float* out = (float*)d_out;

    const int B = in_sizes[0] / (TT * 3);   // 16384
    lstm_fused_kernel<<<dim3(B / NB), dim3(NTH), 0, stream>>>(
        x, W, U, b, W1, b1, W2, b2, out);
}

// Round 2
// 333.223 us; speedup vs baseline: 3.5579x; 3.5579x over previous
//
#include <hip/hip_runtime.h>
#include <math.h>

#define UNITS 64
#define TT 100
#define NB 16          // batch elements per workgroup (one 16-row MFMA tile)
#define NTH 256        // 4 waves; wave w owns gate columns [64w, 64w+64)
#define HSTR 72        // hbuf row stride in halves (64 + 8 pad -> quad offsets 8 banks apart)
#define ZSTR 258       // zbuf row stride in floats (4*258 % 32 == 8 -> no quad conflicts)

typedef _Float16 half8 __attribute__((ext_vector_type(8)));
typedef float floatx4 __attribute__((ext_vector_type(4)));

__device__ __forceinline__ float rcp_fast(float x) { return __builtin_amdgcn_rcpf(x); }

__device__ __forceinline__ float fast_sigmoid(float x) {
    float e = __expf(-x);              // x<<0 -> inf -> rcp=0 ; x>>0 -> 0 -> 1. Safe.
    return rcp_fast(1.0f + e);
}

__device__ __forceinline__ float fast_tanh(float x) {
    float ax = fabsf(x);
    float e = __expf(-2.0f * ax);      // e <= 1, no overflow
    float t = (1.0f - e) * rcp_fast(1.0f + e);
    return copysignf(t, x);
}

__global__ __launch_bounds__(NTH, 4) void lstm_mfma_kernel(
    const float* __restrict__ x,    // (B, 100, 3)
    const float* __restrict__ W,    // (3, 256)
    const float* __restrict__ U,    // (64, 256)
    const float* __restrict__ bias, // (256,)
    const float* __restrict__ W1,   // (64, 64)
    const float* __restrict__ b1,   // (64,)
    const float* __restrict__ W2,   // (64, 5)
    const float* __restrict__ b2,   // (5,)
    float* __restrict__ out)        // (B, 5)
{
    __shared__ __align__(16) _Float16 hbuf[NB * HSTR];  // h state, f16, A-frag order
    __shared__ float zbuf[NB * ZSTR];                   // activated gates; reused as h1
    __shared__ __align__(16) float xbuf[NB * 4];
    __shared__ float maskbuf[NB];
    __shared__ float logitbuf[NB * 5];
    __shared__ int anybuf;

    const int tid = threadIdx.x;
    const int w   = tid >> 6;   // wave = gate class: 0=i 1=f 2=g(tanh) 3=o
    const int l   = tid & 63;
    const int q   = l >> 4;     // quad
    const int cnl = l & 15;     // col within 16-wide tile
    const int b0  = blockIdx.x * NB;

    // ---- one-time preload: B fragments of U (f16) + zx constants ----
    // B-frag layout (16x16x32): lane holds B[k = 32*kb + 8*q + j][n = cnl], j=0..7
    half8 Bf[4][2];
    float bzc[4], Wc0[4], Wc1[4], Wc2[4];
    #pragma unroll
    for (int nt = 0; nt < 4; ++nt) {
        const int g = 64 * w + 16 * nt + cnl;
        bzc[nt] = bias[g];
        Wc0[nt] = W[g]; Wc1[nt] = W[256 + g]; Wc2[nt] = W[512 + g];
        #pragma unroll
        for (int kb = 0; kb < 2; ++kb)
            #pragma unroll
            for (int j = 0; j < 8; ++j)
                Bf[nt][kb][j] = (_Float16)U[(32 * kb + 8 * q + j) * 256 + g];
    }

    // ---- zero initial h ----
    for (int i = tid; i < NB * HSTR; i += NTH) hbuf[i] = (_Float16)0.0f;

    float c[4] = {0.0f, 0.0f, 0.0f, 0.0f};  // c[r] is component (r*256+tid): b=comp>>6, k=comp&63

    #pragma unroll 1
    for (int t = 0; t < TT; ++t) {
        __syncthreads();  // h/zbuf hazards from previous iteration

        bool act = false;
        if (tid < NB) {
            const float* xp = x + (size_t)(b0 + tid) * (TT * 3) + t * 3;
            const float x0 = xp[0], x1 = xp[1], x2 = xp[2];
            xbuf[tid * 4 + 0] = x0;
            xbuf[tid * 4 + 1] = x1;
            xbuf[tid * 4 + 2] = x2;
            xbuf[tid * 4 + 3] = 0.0f;
            act = (x0 != 0.0f) || (x1 != 0.0f) || (x2 != 0.0f);
            maskbuf[tid] = act ? 1.0f : 0.0f;
        }
        if (w == 0) {  // NB=16 lanes all in wave 0
            const unsigned long long bal = __ballot(act ? 1 : 0);
            if (l == 0) anybuf = (bal != 0ULL) ? 1 : 0;
        }
        __syncthreads();
        if (!anybuf) continue;  // whole tile dead (uniform)

        // ---- A fragments from h: lane holds A[m=cnl][k = 32*kb + 8*q + j] ----
        const half8 A0 = *(const half8*)&hbuf[cnl * HSTR + 8 * q];
        const half8 A1 = *(const half8*)&hbuf[cnl * HSTR + 32 + 8 * q];

        // ---- init acc with zx = x@W + b (C layout: row b = 4q+r, col g) ----
        floatx4 acc[4];
        #pragma unroll
        for (int r = 0; r < 4; ++r) {
            const float4 xv = *(const float4*)&xbuf[(4 * q + r) * 4];
            #pragma unroll
            for (int nt = 0; nt < 4; ++nt)
                acc[nt][r] = bzc[nt] + xv.x * Wc0[nt] + xv.y * Wc1[nt] + xv.z * Wc2[nt];
        }

        // ---- Z = H @ U via MFMA (K=64 -> 2 per n-tile) ----
        #pragma unroll
        for (int nt = 0; nt < 4; ++nt) {
            acc[nt] = __builtin_amdgcn_mfma_f32_16x16x32_f16(A0, Bf[nt][0], acc[nt], 0, 0, 0);
            acc[nt] = __builtin_amdgcn_mfma_f32_16x16x32_f16(A1, Bf[nt][1], acc[nt], 0, 0, 0);
        }

        // ---- activation (wave-uniform type) + scatter to zbuf ----
        #pragma unroll
        for (int nt = 0; nt < 4; ++nt) {
            #pragma unroll
            for (int r = 0; r < 4; ++r) {
                const float zv = acc[nt][r];
                const float a  = (w == 2) ? fast_tanh(zv) : fast_sigmoid(zv);
                zbuf[(4 * q + r) * ZSTR + 64 * w + 16 * nt + cnl] = a;
            }
        }
        __syncthreads();

        // ---- c/h update: comp = r*256+tid -> b (wave-uniform), k = lane ----
        #pragma unroll
        for (int r = 0; r < 4; ++r) {
            const int comp = r * NTH + tid;
            const int b = comp >> 6;
            const int k = comp & 63;
            if (maskbuf[b] != 0.0f) {
                const float iv = zbuf[b * ZSTR +       k];
                const float fv = zbuf[b * ZSTR +  64 + k];
                const float gv = zbuf[b * ZSTR + 128 + k];
                const float ov = zbuf[b * ZSTR + 192 + k];
                const float cnew = fv * c[r] + iv * gv;
                c[r] = cnew;
                hbuf[b * HSTR + k] = (_Float16)(ov * fast_tanh(cnew));
            }
        }
    }
    __syncthreads();

    // ---- epilogue: h1 = relu(h @ W1 + b1) into zbuf (stride 64) ----
    {
        const int j  = tid & 63;
        const int bb = tid >> 6;  // 0..3
        const float bj = b1[j];
        #pragma unroll
        for (int p = 0; p < NB / 4; ++p) {
            const int b = p * 4 + bb;
            float acc = bj;
            #pragma unroll 8
            for (int k = 0; k < UNITS; ++k)
                acc += (float)hbuf[b * HSTR + k] * W1[k * 64 + j];  // hbuf broadcast, W1 coalesced
            zbuf[b * 64 + j] = fmaxf(acc, 0.0f);
        }
    }
    __syncthreads();

    // ---- logits = h1 @ W2 + b2 ----
    if (tid < NB * 5) {
        const int b = tid / 5, s = tid % 5;
        float acc = b2[s];
        for (int j = 0; j < 64; ++j)
            acc += zbuf[b * 64 + j] * W2[j * 5 + s];
        logitbuf[b * 5 + s] = acc;
    }
    __syncthreads();

    // ---- softmax over 5 ----
    if (tid < NB) {
        const float l0 = logitbuf[tid * 5 + 0];
        const float l1 = logitbuf[tid * 5 + 1];
        const float l2 = logitbuf[tid * 5 + 2];
        const float l3 = logitbuf[tid * 5 + 3];
        const float l4 = logitbuf[tid * 5 + 4];
        const float m  = fmaxf(fmaxf(fmaxf(l0, l1), fmaxf(l2, l3)), l4);
        const float e0 = __expf(l0 - m), e1 = __expf(l1 - m), e2 = __expf(l2 - m);
        const float e3 = __expf(l3 - m), e4 = __expf(l4 - m);
        const float rs = 1.0f / (e0 + e1 + e2 + e3 + e4);
        const int gb = b0 + tid;
        out[gb * 5 + 0] = e0 * rs;
        out[gb * 5 + 1] = e1 * rs;
        out[gb * 5 + 2] = e2 * rs;
        out[gb * 5 + 3] = e3 * rs;
        out[gb * 5 + 4] = e4 * rs;
    }
}

extern "C" void kernel_launch(void* const* d_in, const int* in_sizes, int n_in,
                              void* d_out, int out_size, void* d_ws, size_t ws_size,
                              hipStream_t stream) {
    const float* x  = (const float*)d_in[0];
    const float* W  = (const float*)d_in[1];
    const float* U  = (const float*)d_in[2];
    const float* b  = (const float*)d_in[3];
    const float* W1 = (const float*)d_in[4];
    const float* b1 = (const float*)d_in[5];
    const float* W2 = (const float*)d_in[6];
    const float* b2 = (const float*)d_in[7];
    float* out = (float*)d_out;

    const int B = in_sizes[0] / (TT * 3);   // 16384
    lstm_mfma_kernel<<<dim3(B / NB), dim3(NTH), 0, stream>>>(
        x, W, U, b, W1, b1, W2, b2, out);
}

// Round 3
// 315.545 us; speedup vs baseline: 3.7572x; 1.0560x over previous
//
#include <hip/hip_runtime.h>
#include <math.h>

#define UNITS 64
#define TT 100
#define NB 16          // batch rows per workgroup = one MFMA M-tile
#define NTH 256        // 4 waves; wave w owns unit-columns [16w, 16w+16) for ALL 4 gates
#define HSTR 72        // hbuf row stride in halves (rows stay 16B-aligned)

typedef _Float16 half8 __attribute__((ext_vector_type(8)));
typedef float floatx4 __attribute__((ext_vector_type(4)));

#define LOG2E 1.44269504088896f

__device__ __forceinline__ float rcp_fast(float x) { return __builtin_amdgcn_rcpf(x); }

__device__ __forceinline__ float fast_sigmoid(float x) {
    // 1/(1+2^(-x*log2e)); saturates correctly at +-inf.
    float e = exp2f(-LOG2E * x);
    return rcp_fast(1.0f + e);
}

__device__ __forceinline__ float fast_tanh(float x) {
    // tanh(x) = 2/(1+2^(-2x*log2e)) - 1; handles both signs, no overflow path.
    float e = exp2f(-2.0f * LOG2E * x);
    return __builtin_fmaf(2.0f, rcp_fast(1.0f + e), -1.0f);
}

__global__ __launch_bounds__(NTH, 4) void lstm_mfma_kernel(
    const float* __restrict__ x,    // (B, 100, 3)
    const float* __restrict__ W,    // (3, 256)
    const float* __restrict__ U,    // (64, 256)
    const float* __restrict__ bias, // (256,)
    const float* __restrict__ W1,   // (64, 64)
    const float* __restrict__ b1,   // (64,)
    const float* __restrict__ W2,   // (64, 5)
    const float* __restrict__ b2,   // (5,)
    float* __restrict__ out)        // (B, 5)
{
    __shared__ __align__(16) _Float16 hbuf[NB * HSTR];  // h state (f16), 2.3 KB
    __shared__ __align__(16) float xbuf[NB * 4];        // current x rows
    __shared__ float h1buf[NB * 64];                    // epilogue h1
    __shared__ float logitbuf[NB * 5];

    const int tid = threadIdx.x;
    const int w   = tid >> 6;   // wave -> unit-column slice
    const int l   = tid & 63;
    const int q   = l >> 4;     // quad
    const int cnl = l & 15;     // col within 16-wide tile
    const int b0  = blockIdx.x * NB;

    // ---- one-time preload: per-gate B fragments of U + zx constants ----
    // Wave w's z-column for gate g: zc = 64g + 16w + cnl.
    // B-frag (16x16x32): lane holds B[k = 32*kb + 8*q + j][n], j=0..7.
    half8 Bf[4][2];
    float bz[4], Wc0[4], Wc1[4], Wc2[4];
    #pragma unroll
    for (int g = 0; g < 4; ++g) {
        const int zc = 64 * g + 16 * w + cnl;
        bz[g]  = bias[zc];
        Wc0[g] = W[zc]; Wc1[g] = W[256 + zc]; Wc2[g] = W[512 + zc];
        #pragma unroll
        for (int kb = 0; kb < 2; ++kb)
            #pragma unroll
            for (int j = 0; j < 8; ++j)
                Bf[g][kb][j] = (_Float16)U[(32 * kb + 8 * q + j) * 256 + zc];
    }

    // ---- zero initial h; c state in registers (row 4q+r, col 16w+cnl) ----
    for (int i = tid; i < NB * HSTR; i += NTH) hbuf[i] = (_Float16)0.0f;
    float c4[4] = {0.0f, 0.0f, 0.0f, 0.0f};

    // ---- prefetch x(0) into registers (tid<NB only) ----
    float px0 = 0.0f, px1 = 0.0f, px2 = 0.0f;
    if (tid < NB) {
        const float* xp = x + (size_t)(b0 + tid) * (TT * 3);
        px0 = xp[0]; px1 = xp[1]; px2 = xp[2];
    }

    #pragma unroll 1
    for (int t = 0; t < TT; ++t) {
        // publish x(t) (same barrier interval as prev iter's h-write; disjoint buffer)
        if (tid < NB) {
            xbuf[tid * 4 + 0] = px0;
            xbuf[tid * 4 + 1] = px1;
            xbuf[tid * 4 + 2] = px2;
            xbuf[tid * 4 + 3] = 0.0f;
        }
        __syncthreads();   // B1: h(t-1) writes + xbuf(t) visible

        // A fragments of h: lane holds A[m=cnl][k = 32*kb + 8q + j]
        const half8 A0 = *(const half8*)&hbuf[cnl * HSTR + 8 * q];
        const half8 A1 = *(const half8*)&hbuf[cnl * HSTR + 32 + 8 * q];

        // acc init with zx = x@W + b (C layout: row 4q+r, col 16w+cnl); mask in-reg
        floatx4 acc[4];
        float msk[4];
        #pragma unroll
        for (int r = 0; r < 4; ++r) {
            const float4 xv = *(const float4*)&xbuf[(4 * q + r) * 4];  // broadcast
            msk[r] = (xv.x != 0.0f || xv.y != 0.0f || xv.z != 0.0f) ? 1.0f : 0.0f;
            #pragma unroll
            for (int g = 0; g < 4; ++g)
                acc[g][r] = bz[g] + xv.x * Wc0[g] + xv.y * Wc1[g] + xv.z * Wc2[g];
        }

        // prefetch x(t+1) (global, overlaps MFMA/activation latency)
        if (tid < NB) {
            const int tp = (t + 1 < TT) ? (t + 1) : (TT - 1);
            const float* xp = x + (size_t)(b0 + tid) * (TT * 3) + 3 * tp;
            px0 = xp[0]; px1 = xp[1]; px2 = xp[2];
        }

        // Z = H @ U via MFMA: 4 gates x (K=64 -> 2 MFMAs)
        #pragma unroll
        for (int g = 0; g < 4; ++g) {
            acc[g] = __builtin_amdgcn_mfma_f32_16x16x32_f16(A0, Bf[g][0], acc[g], 0, 0, 0);
            acc[g] = __builtin_amdgcn_mfma_f32_16x16x32_f16(A1, Bf[g][1], acc[g], 0, 0, 0);
        }

        // in-register gate activation + c/h update (gate type is compile-time)
        _Float16 hnew[4];
        #pragma unroll
        for (int r = 0; r < 4; ++r) {
            const float iv = fast_sigmoid(acc[0][r]);
            const float fv = fast_sigmoid(acc[1][r]);
            const float gv = fast_tanh  (acc[2][r]);
            const float ov = fast_sigmoid(acc[3][r]);
            const float cn = fv * c4[r] + iv * gv;
            c4[r] = (msk[r] != 0.0f) ? cn : c4[r];
            hnew[r] = (_Float16)(ov * fast_tanh(cn));
        }

        __syncthreads();   // B2: all reads of hbuf/xbuf for step t done
        #pragma unroll
        for (int r = 0; r < 4; ++r)
            if (msk[r] != 0.0f)
                hbuf[(4 * q + r) * HSTR + 16 * w + cnl] = hnew[r];  // h stays old when masked
    }
    __syncthreads();

    // ---- epilogue: h1 = relu(h @ W1 + b1) ----
    {
        const int j  = tid & 63;
        const int bb = tid >> 6;  // 0..3
        const float bj = b1[j];
        #pragma unroll
        for (int p = 0; p < NB / 4; ++p) {
            const int b = p * 4 + bb;
            float acc = bj;
            #pragma unroll 8
            for (int k = 0; k < UNITS; ++k)
                acc += (float)hbuf[b * HSTR + k] * W1[k * 64 + j];  // hbuf broadcast, W1 coalesced
            h1buf[b * 64 + j] = fmaxf(acc, 0.0f);
        }
    }
    __syncthreads();

    // ---- logits = h1 @ W2 + b2 ----
    if (tid < NB * 5) {
        const int b = tid / 5, s = tid % 5;
        float acc = b2[s];
        for (int j = 0; j < 64; ++j)
            acc += h1buf[b * 64 + j] * W2[j * 5 + s];
        logitbuf[b * 5 + s] = acc;
    }
    __syncthreads();

    // ---- softmax over 5 ----
    if (tid < NB) {
        const float l0 = logitbuf[tid * 5 + 0];
        const float l1 = logitbuf[tid * 5 + 1];
        const float l2 = logitbuf[tid * 5 + 2];
        const float l3 = logitbuf[tid * 5 + 3];
        const float l4 = logitbuf[tid * 5 + 4];
        const float m  = fmaxf(fmaxf(fmaxf(l0, l1), fmaxf(l2, l3)), l4);
        const float e0 = __expf(l0 - m), e1 = __expf(l1 - m), e2 = __expf(l2 - m);
        const float e3 = __expf(l3 - m), e4 = __expf(l4 - m);
        const float rs = 1.0f / (e0 + e1 + e2 + e3 + e4);
        const int gb = b0 + tid;
        out[gb * 5 + 0] = e0 * rs;
        out[gb * 5 + 1] = e1 * rs;
        out[gb * 5 + 2] = e2 * rs;
        out[gb * 5 + 3] = e3 * rs;
        out[gb * 5 + 4] = e4 * rs;
    }
}

extern "C" void kernel_launch(void* const* d_in, const int* in_sizes, int n_in,
                              void* d_out, int out_size, void* d_ws, size_t ws_size,
                              hipStream_t stream) {
    const float* x  = (const float*)d_in[0];
    const float* W  = (const float*)d_in[1];
    const float* U  = (const float*)d_in[2];
    const float* b  = (const float*)d_in[3];
    const float* W1 = (const float*)d_in[4];
    const float* b1 = (const float*)d_in[5];
    const float* W2 = (const float*)d_in[6];
    const float* b2 = (const float*)d_in[7];
    float* out = (float*)d_out;

    const int B = in_sizes[0] / (TT * 3);   // 16384
    lstm_mfma_kernel<<<dim3(B / NB), dim3(NTH), 0, stream>>>(
        x, W, U, b, W1, b1, W2, b2, out);
}

// Round 5
// 305.476 us; speedup vs baseline: 3.8811x; 1.0330x over previous
//
#include <hip/hip_runtime.h>
#include <math.h>

#define UNITS 64
#define TT 100
#define NB 16          // batch rows per workgroup = one MFMA M-tile
#define NTH 256        // 4 waves; wave w owns unit-columns [16w, 16w+16) for ALL 4 gates
#define HSTR 72        // hbuf row stride in halves (rows stay 16B-aligned)

typedef _Float16 half8 __attribute__((ext_vector_type(8)));
typedef float floatx4 __attribute__((ext_vector_type(4)));

#define LOG2E 1.44269504088896f

__device__ __forceinline__ float rcp_fast(float x) { return __builtin_amdgcn_rcpf(x); }

__device__ __forceinline__ float fast_sigmoid(float x) {
    float e = exp2f(-LOG2E * x);       // saturates correctly at +-inf
    return rcp_fast(1.0f + e);
}

__device__ __forceinline__ float fast_tanh(float x) {
    float e = exp2f(-2.0f * LOG2E * x);
    return __builtin_fmaf(2.0f, rcp_fast(1.0f + e), -1.0f);
}

// ---- prologue kernel 1: per-batch length (= 1 + last t with any x!=0) ----
__global__ __launch_bounds__(256) void len_kernel(
    const float* __restrict__ x, int* __restrict__ len, int* __restrict__ hist, int B)
{
    const int wave = blockIdx.x * 4 + (threadIdx.x >> 6);
    const int l = threadIdx.x & 63;
    if (wave >= B) return;
    const float* xp = x + (size_t)wave * (TT * 3);
    int m = 0;
    #pragma unroll
    for (int t = l; t < TT; t += 64) {          // lanes read 12B contiguous -> coalesced
        const float a = xp[3 * t], b = xp[3 * t + 1], c = xp[3 * t + 2];
        if (a != 0.0f || b != 0.0f || c != 0.0f) m = t + 1;
    }
    #pragma unroll
    for (int off = 32; off; off >>= 1)
        m = max(m, __shfl_down(m, off, 64));
    if (l == 0) { len[wave] = m; atomicAdd(&hist[m], 1); }
}

// ---- prologue kernel 2: descending-length offsets into a SEPARATE buffer ----
// (round-4 bug: in-place hist->hist had a cross-wave read/write race)
__global__ void offs_kernel(const int* __restrict__ hist, int* __restrict__ offs)
{
    const int l = threadIdx.x;
    if (l <= TT) {
        int s = 0;
        for (int k = l + 1; k <= TT; ++k) s += hist[k];
        offs[l] = s;                            // rank offset of length-l group (descending)
    }
}

// ---- prologue kernel 3: scatter permutation ----
__global__ __launch_bounds__(256) void scatter_kernel(
    const int* __restrict__ len, const int* __restrict__ offs, int* __restrict__ cursor,
    int* __restrict__ perm, int* __restrict__ rlen, int B)
{
    const int b = blockIdx.x * 256 + threadIdx.x;
    if (b < B) {
        const int l = len[b];
        const int r = offs[l] + atomicAdd(&cursor[l], 1);
        if (r >= 0 && r < B) { perm[r] = b; rlen[r] = l; }
    }
}

__global__ __launch_bounds__(NTH, 4) void lstm_mfma_kernel(
    const float* __restrict__ x,    // (B, 100, 3)
    const float* __restrict__ W,    // (3, 256)
    const float* __restrict__ U,    // (64, 256)
    const float* __restrict__ bias, // (256,)
    const float* __restrict__ W1,   // (64, 64)
    const float* __restrict__ b1,   // (64,)
    const float* __restrict__ W2,   // (64, 5)
    const float* __restrict__ b2,   // (5,)
    const int*   __restrict__ perm, // (B,) rank -> batch, descending length (may be null)
    const int*   __restrict__ rlen, // (B,) length at rank (may be null)
    float* __restrict__ out,        // (B, 5)
    int B)
{
    __shared__ __align__(16) _Float16 hbuf[NB * HSTR];
    __shared__ __align__(16) float xbuf[NB * 4];
    __shared__ float h1buf[NB * 64];
    __shared__ float logitbuf[NB * 5];

    const int tid = threadIdx.x;
    const int w   = tid >> 6;
    const int l   = tid & 63;
    const int q   = l >> 4;
    const int cnl = l & 15;
    const int b0  = blockIdx.x * NB;

    // tile max length (descending sort -> first rank of tile)
    int maxlen = rlen ? rlen[b0] : TT;
    maxlen = (maxlen < 0) ? 0 : ((maxlen > TT) ? TT : maxlen);

    // this lane's batch row (only meaningful for tid<NB)
    int gb = b0 + tid;
    if (perm && tid < NB) gb = perm[b0 + tid];
    gb = (gb < 0) ? 0 : ((gb >= B) ? (B - 1) : gb);   // degrade bugs to wrong answer, not fault
    const float* xrow = x + (size_t)gb * (TT * 3);

    // ---- one-time preload: per-gate B fragments of U + zx constants ----
    half8 Bf[4][2];
    float bz[4], Wc0[4], Wc1[4], Wc2[4];
    #pragma unroll
    for (int g = 0; g < 4; ++g) {
        const int zc = 64 * g + 16 * w + cnl;
        bz[g]  = bias[zc];
        Wc0[g] = W[zc]; Wc1[g] = W[256 + zc]; Wc2[g] = W[512 + zc];
        #pragma unroll
        for (int kb = 0; kb < 2; ++kb)
            #pragma unroll
            for (int j = 0; j < 8; ++j)
                Bf[g][kb][j] = (_Float16)U[(32 * kb + 8 * q + j) * 256 + zc];
    }

    for (int i = tid; i < NB * HSTR; i += NTH) hbuf[i] = (_Float16)0.0f;
    float c4[4] = {0.0f, 0.0f, 0.0f, 0.0f};

    float px0 = 0.0f, px1 = 0.0f, px2 = 0.0f;
    if (tid < NB) { px0 = xrow[0]; px1 = xrow[1]; px2 = xrow[2]; }

    #pragma unroll 1
    for (int t = 0; t < maxlen; ++t) {
        if (tid < NB) {
            xbuf[tid * 4 + 0] = px0;
            xbuf[tid * 4 + 1] = px1;
            xbuf[tid * 4 + 2] = px2;
            xbuf[tid * 4 + 3] = 0.0f;
        }
        __syncthreads();   // B1: h(t-1) writes + xbuf(t) visible

        const half8 A0 = *(const half8*)&hbuf[cnl * HSTR + 8 * q];
        const half8 A1 = *(const half8*)&hbuf[cnl * HSTR + 32 + 8 * q];

        floatx4 acc[4];
        float msk[4];
        #pragma unroll
        for (int r = 0; r < 4; ++r) {
            const float4 xv = *(const float4*)&xbuf[(4 * q + r) * 4];
            msk[r] = (xv.x != 0.0f || xv.y != 0.0f || xv.z != 0.0f) ? 1.0f : 0.0f;
            #pragma unroll
            for (int g = 0; g < 4; ++g)
                acc[g][r] = bz[g] + xv.x * Wc0[g] + xv.y * Wc1[g] + xv.z * Wc2[g];
        }

        if (tid < NB) {
            const int tp = (t + 1 < TT) ? (t + 1) : (TT - 1);
            const float* xp = xrow + 3 * tp;
            px0 = xp[0]; px1 = xp[1]; px2 = xp[2];
        }

        #pragma unroll
        for (int g = 0; g < 4; ++g) {
            acc[g] = __builtin_amdgcn_mfma_f32_16x16x32_f16(A0, Bf[g][0], acc[g], 0, 0, 0);
            acc[g] = __builtin_amdgcn_mfma_f32_16x16x32_f16(A1, Bf[g][1], acc[g], 0, 0, 0);
        }

        _Float16 hnew[4];
        #pragma unroll
        for (int r = 0; r < 4; ++r) {
            const float iv = fast_sigmoid(acc[0][r]);
            const float fv = fast_sigmoid(acc[1][r]);
            const float gv = fast_tanh  (acc[2][r]);
            const float ov = fast_sigmoid(acc[3][r]);
            const float cn = fv * c4[r] + iv * gv;
            c4[r] = (msk[r] != 0.0f) ? cn : c4[r];
            hnew[r] = (_Float16)(ov * fast_tanh(cn));
        }

        __syncthreads();   // B2: all reads of hbuf/xbuf for step t done
        #pragma unroll
        for (int r = 0; r < 4; ++r)
            if (msk[r] != 0.0f)
                hbuf[(4 * q + r) * HSTR + 16 * w + cnl] = hnew[r];
    }
    __syncthreads();

    // ---- epilogue: h1 = relu(h @ W1 + b1) ----
    {
        const int j  = tid & 63;
        const int bb = tid >> 6;
        const float bj = b1[j];
        #pragma unroll
        for (int p = 0; p < NB / 4; ++p) {
            const int b = p * 4 + bb;
            float acc = bj;
            #pragma unroll 8
            for (int k = 0; k < UNITS; ++k)
                acc += (float)hbuf[b * HSTR + k] * W1[k * 64 + j];
            h1buf[b * 64 + j] = fmaxf(acc, 0.0f);
        }
    }
    __syncthreads();

    if (tid < NB * 5) {
        const int b = tid / 5, s = tid % 5;
        float acc = b2[s];
        for (int j = 0; j < 64; ++j)
            acc += h1buf[b * 64 + j] * W2[j * 5 + s];
        logitbuf[b * 5 + s] = acc;
    }
    __syncthreads();

    if (tid < NB) {
        const float l0 = logitbuf[tid * 5 + 0];
        const float l1 = logitbuf[tid * 5 + 1];
        const float l2 = logitbuf[tid * 5 + 2];
        const float l3 = logitbuf[tid * 5 + 3];
        const float l4 = logitbuf[tid * 5 + 4];
        const float m  = fmaxf(fmaxf(fmaxf(l0, l1), fmaxf(l2, l3)), l4);
        const float e0 = __expf(l0 - m), e1 = __expf(l1 - m), e2 = __expf(l2 - m);
        const float e3 = __expf(l3 - m), e4 = __expf(l4 - m);
        const float rs = 1.0f / (e0 + e1 + e2 + e3 + e4);
        out[(size_t)gb * 5 + 0] = e0 * rs;
        out[(size_t)gb * 5 + 1] = e1 * rs;
        out[(size_t)gb * 5 + 2] = e2 * rs;
        out[(size_t)gb * 5 + 3] = e3 * rs;
        out[(size_t)gb * 5 + 4] = e4 * rs;
    }
}

extern "C" void kernel_launch(void* const* d_in, const int* in_sizes, int n_in,
                              void* d_out, int out_size, void* d_ws, size_t ws_size,
                              hipStream_t stream) {
    const float* x  = (const float*)d_in[0];
    const float* W  = (const float*)d_in[1];
    const float* U  = (const float*)d_in[2];
    const float* b  = (const float*)d_in[3];
    const float* W1 = (const float*)d_in[4];
    const float* b1 = (const float*)d_in[5];
    const float* W2 = (const float*)d_in[6];
    const float* b2 = (const float*)d_in[7];
    float* out = (float*)d_out;

    const int B = in_sizes[0] / (TT * 3);   // 16384

    // workspace layout (ints): len[B], perm[B], rlen[B], hist[128], offs[128], cursor[128]
    const size_t need = ((size_t)3 * B + 384) * sizeof(int);
    int* perm = nullptr; int* rlen = nullptr;

    if (ws_size >= need) {
        int* len    = (int*)d_ws;
        perm        = len + B;
        rlen        = perm + B;
        int* hist   = rlen + B;
        int* offs   = hist + 128;
        int* cursor = offs + 128;

        hipMemsetAsync(hist, 0, 384 * sizeof(int), stream);  // hist + offs + cursor
        len_kernel<<<dim3((B + 3) / 4), dim3(256), 0, stream>>>(x, len, hist, B);
        offs_kernel<<<dim3(1), dim3(128), 0, stream>>>(hist, offs);   // separate out buffer
        scatter_kernel<<<dim3((B + 255) / 256), dim3(256), 0, stream>>>(len, offs, cursor, perm, rlen, B);
    }

    lstm_mfma_kernel<<<dim3(B / NB), dim3(NTH), 0, stream>>>(
        x, W, U, b, W1, b1, W2, b2, perm, rlen, out, B);
}

// Round 6
// 223.732 us; speedup vs baseline: 5.2991x; 1.3654x over previous
//
#include <hip/hip_runtime.h>
#include <math.h>

#define UNITS 64
#define TT 100
#define NB 16          // batch rows per workgroup = one MFMA M-tile
#define NTH 256        // 4 waves; wave w owns unit-columns [16w, 16w+16) for ALL 4 gates
#define HSTR 72        // hbuf row stride in halves (rows stay 16B-aligned)
#define XSTR 32        // xh row stride in halves (64B rows; broadcast-friendly)

typedef _Float16 half8 __attribute__((ext_vector_type(8)));
typedef _Float16 half4 __attribute__((ext_vector_type(4)));
typedef float floatx4 __attribute__((ext_vector_type(4)));

#define LOG2E 1.44269504088896f

__device__ __forceinline__ float rcp_fast(float x) { return __builtin_amdgcn_rcpf(x); }
__device__ __forceinline__ float exp2_fast(float x) { return __builtin_amdgcn_exp2f(x); }

__device__ __forceinline__ float fast_sigmoid(float x) {
    // 1/(1+2^(-x*log2e)); v_exp_f32 handles +-inf -> saturates to 0/1 correctly.
    return rcp_fast(1.0f + exp2_fast(-LOG2E * x));
}

__device__ __forceinline__ float fast_tanh(float x) {
    return __builtin_fmaf(2.0f, rcp_fast(1.0f + exp2_fast(-2.0f * LOG2E * x)), -1.0f);
}

// ---- prologue 1: per-batch length (= 1 + last t with any x!=0), no atomics ----
__global__ __launch_bounds__(256) void len_kernel(
    const float* __restrict__ x, int* __restrict__ len, int B)
{
    const int row = blockIdx.x * 4 + (threadIdx.x >> 6);
    const int l = threadIdx.x & 63;
    if (row >= B) return;
    const float* xp = x + (size_t)row * (TT * 3);
    int m = 0;
    #pragma unroll
    for (int t = l; t < TT; t += 64) {          // 12B/lane contiguous -> coalesced
        const float a = xp[3 * t], b = xp[3 * t + 1], c = xp[3 * t + 2];
        if (a != 0.0f || b != 0.0f || c != 0.0f) m = t + 1;
    }
    #pragma unroll
    for (int off = 32; off; off >>= 1)
        m = max(m, __shfl_down(m, off, 64));
    if (l == 0) len[row] = m;
}

// ---- prologue 2: single-block counting sort (hist + offsets + scatter in LDS) ----
__global__ __launch_bounds__(256) void sort_kernel(
    const int* __restrict__ len, int* __restrict__ perm, int* __restrict__ rlen, int B)
{
    __shared__ int sh_hist[TT + 1];
    __shared__ int sh_base[TT + 1];
    const int tid = threadIdx.x;

    for (int i = tid; i <= TT; i += 256) sh_hist[i] = 0;
    __syncthreads();
    for (int b = tid; b < B; b += 256) atomicAdd(&sh_hist[len[b]], 1);
    __syncthreads();
    if (tid <= TT) {             // descending-length group offsets (separate array, no race)
        int s = 0;
        for (int k = tid + 1; k <= TT; ++k) s += sh_hist[k];
        sh_base[tid] = s;
    }
    __syncthreads();
    for (int b = tid; b < B; b += 256) {
        const int l = len[b];
        const int r = sh_base[l] + atomicAdd(&sh_hist[l], -1) - 1;  // hist doubles as cursor
        if (r >= 0 && r < B) { perm[r] = b; rlen[r] = l; }
    }
}

__global__ __launch_bounds__(NTH, 4) void lstm_mfma_kernel(
    const float* __restrict__ x,    // (B, 100, 3)
    const float* __restrict__ W,    // (3, 256)
    const float* __restrict__ U,    // (64, 256)
    const float* __restrict__ bias, // (256,)
    const float* __restrict__ W1,   // (64, 64)
    const float* __restrict__ b1,   // (64,)
    const float* __restrict__ W2,   // (64, 5)
    const float* __restrict__ b2,   // (5,)
    const int*   __restrict__ perm, // (B,) rank -> batch, descending length (may be null)
    const int*   __restrict__ rlen, // (B,) length at rank (may be null)
    float* __restrict__ out,        // (B, 5)
    int B)
{
    __shared__ __align__(16) _Float16 hbuf[NB * HSTR];   // h state (f16)
    __shared__ __align__(16) _Float16 xh[NB * XSTR];     // [x0,x1,x2,1, 0...] per row (f16)
    __shared__ float maskbuf[NB];
    __shared__ float h1buf[NB * 64];
    __shared__ float logitbuf[NB * 5];

    const int tid = threadIdx.x;
    const int w   = tid >> 6;
    const int l   = tid & 63;
    const int q   = l >> 4;
    const int cnl = l & 15;
    const int b0  = blockIdx.x * NB;

    int maxlen = rlen ? rlen[b0] : TT;
    maxlen = (maxlen < 0) ? 0 : ((maxlen > TT) ? TT : maxlen);

    int gb = b0 + tid;
    if (perm && tid < NB) gb = perm[b0 + tid];
    gb = (gb < 0) ? 0 : ((gb >= B) ? (B - 1) : gb);
    const float* xrow = x + (size_t)gb * (TT * 3);

    // ---- one-time preload: extended-K B fragments. Rows 0..63 = U, 64..66 = W,
    // 67 = bias, 68..95 = 0.  B-frag (16x16x32): lane holds B[k=32kb+8q+j][col].
    half8 Bf[4][3];
    #pragma unroll
    for (int g = 0; g < 4; ++g) {
        const int zc = 64 * g + 16 * w + cnl;
        #pragma unroll
        for (int kb = 0; kb < 3; ++kb)
            #pragma unroll
            for (int j = 0; j < 8; ++j) {
                const int k = 32 * kb + 8 * q + j;
                float v = 0.0f;
                if (k < 64)       v = U[k * 256 + zc];
                else if (k < 67)  v = W[(k - 64) * 256 + zc];
                else if (k == 67) v = bias[zc];
                Bf[g][kb][j] = (_Float16)v;
            }
    }

    for (int i = tid; i < NB * HSTR; i += NTH) hbuf[i] = (_Float16)0.0f;
    for (int i = tid; i < NB * XSTR; i += NTH) xh[i] = (_Float16)0.0f;  // tail stays 0 forever
    float c4[4] = {0.0f, 0.0f, 0.0f, 0.0f};
    const floatx4 zero4 = {0.0f, 0.0f, 0.0f, 0.0f};

    float px0 = 0.0f, px1 = 0.0f, px2 = 0.0f;
    if (tid < NB) { px0 = xrow[0]; px1 = xrow[1]; px2 = xrow[2]; }
    __syncthreads();   // xh zeros visible before first publisher write

    #pragma unroll 1
    for (int t = 0; t < maxlen; ++t) {
        if (tid < NB) {
            half4 xv4 = { (_Float16)px0, (_Float16)px1, (_Float16)px2, (_Float16)1.0f };
            *(half4*)&xh[tid * XSTR] = xv4;                    // one ds_write_b64
            maskbuf[tid] = (px0 != 0.0f || px1 != 0.0f || px2 != 0.0f) ? 1.0f : 0.0f;
        }
        __syncthreads();   // B1: h(t-1) writes + xh/mask(t) visible

        // A fragments: lane holds A[m=cnl][k = 32*kb + 8q + j]
        const half8 A0 = *(const half8*)&hbuf[cnl * HSTR + 8 * q];
        const half8 A1 = *(const half8*)&hbuf[cnl * HSTR + 32 + 8 * q];
        const half8 AX = *(const half8*)&xh[cnl * XSTR + 8 * q];  // x|1 block (q==0 lanes)

        float msk[4];
        #pragma unroll
        for (int r = 0; r < 4; ++r) msk[r] = maskbuf[4 * q + r];  // broadcast b32

        if (tid < NB) {   // prefetch x(t+1), overlaps MFMA latency
            const int tp = (t + 1 < TT) ? (t + 1) : (TT - 1);
            const float* xp = xrow + 3 * tp;
            px0 = xp[0]; px1 = xp[1]; px2 = xp[2];
        }

        // Z = [H | x 1 0] @ [U; W; b; 0]: 3 MFMAs per gate, C of first = const zero regs
        floatx4 acc[4];
        #pragma unroll
        for (int g = 0; g < 4; ++g) {
            acc[g] = __builtin_amdgcn_mfma_f32_16x16x32_f16(AX, Bf[g][2], zero4, 0, 0, 0);
            acc[g] = __builtin_amdgcn_mfma_f32_16x16x32_f16(A0, Bf[g][0], acc[g], 0, 0, 0);
            acc[g] = __builtin_amdgcn_mfma_f32_16x16x32_f16(A1, Bf[g][1], acc[g], 0, 0, 0);
        }

        _Float16 hnew[4];
        #pragma unroll
        for (int r = 0; r < 4; ++r) {
            const float iv = fast_sigmoid(acc[0][r]);
            const float fv = fast_sigmoid(acc[1][r]);
            const float gv = fast_tanh  (acc[2][r]);
            const float ov = fast_sigmoid(acc[3][r]);
            const float cn = fv * c4[r] + iv * gv;
            c4[r] = (msk[r] != 0.0f) ? cn : c4[r];
            hnew[r] = (_Float16)(ov * fast_tanh(cn));
        }

        __syncthreads();   // B2: all reads of hbuf/xh for step t done
        #pragma unroll
        for (int r = 0; r < 4; ++r)
            if (msk[r] != 0.0f)
                hbuf[(4 * q + r) * HSTR + 16 * w + cnl] = hnew[r];
    }
    __syncthreads();

    // ---- epilogue: h1 = relu(h @ W1 + b1) ----
    {
        const int j  = tid & 63;
        const int bb = tid >> 6;
        const float bj = b1[j];
        #pragma unroll
        for (int p = 0; p < NB / 4; ++p) {
            const int b = p * 4 + bb;
            float acc = bj;
            #pragma unroll 8
            for (int k = 0; k < UNITS; ++k)
                acc += (float)hbuf[b * HSTR + k] * W1[k * 64 + j];
            h1buf[b * 64 + j] = fmaxf(acc, 0.0f);
        }
    }
    __syncthreads();

    if (tid < NB * 5) {
        const int b = tid / 5, s = tid % 5;
        float acc = b2[s];
        for (int j = 0; j < 64; ++j)
            acc += h1buf[b * 64 + j] * W2[j * 5 + s];
        logitbuf[b * 5 + s] = acc;
    }
    __syncthreads();

    if (tid < NB) {
        const float l0 = logitbuf[tid * 5 + 0];
        const float l1 = logitbuf[tid * 5 + 1];
        const float l2 = logitbuf[tid * 5 + 2];
        const float l3 = logitbuf[tid * 5 + 3];
        const float l4 = logitbuf[tid * 5 + 4];
        const float m  = fmaxf(fmaxf(fmaxf(l0, l1), fmaxf(l2, l3)), l4);
        const float e0 = __expf(l0 - m), e1 = __expf(l1 - m), e2 = __expf(l2 - m);
        const float e3 = __expf(l3 - m), e4 = __expf(l4 - m);
        const float rs = 1.0f / (e0 + e1 + e2 + e3 + e4);
        out[(size_t)gb * 5 + 0] = e0 * rs;
        out[(size_t)gb * 5 + 1] = e1 * rs;
        out[(size_t)gb * 5 + 2] = e2 * rs;
        out[(size_t)gb * 5 + 3] = e3 * rs;
        out[(size_t)gb * 5 + 4] = e4 * rs;
    }
}

extern "C" void kernel_launch(void* const* d_in, const int* in_sizes, int n_in,
                              void* d_out, int out_size, void* d_ws, size_t ws_size,
                              hipStream_t stream) {
    const float* x  = (const float*)d_in[0];
    const float* W  = (const float*)d_in[1];
    const float* U  = (const float*)d_in[2];
    const float* b  = (const float*)d_in[3];
    const float* W1 = (const float*)d_in[4];
    const float* b1 = (const float*)d_in[5];
    const float* W2 = (const float*)d_in[6];
    const float* b2 = (const float*)d_in[7];
    float* out = (float*)d_out;

    const int B = in_sizes[0] / (TT * 3);   // 16384

    // workspace layout (ints): len[B], perm[B], rlen[B]
    const size_t need = (size_t)3 * B * sizeof(int);
    int* perm = nullptr; int* rlen = nullptr;

    if (ws_size >= need) {
        int* len = (int*)d_ws;
        perm     = len + B;
        rlen     = perm + B;
        len_kernel<<<dim3((B + 3) / 4), dim3(256), 0, stream>>>(x, len, B);
        sort_kernel<<<dim3(1), dim3(256), 0, stream>>>(len, perm, rlen, B);
    }

    lstm_mfma_kernel<<<dim3(B / NB), dim3(NTH), 0, stream>>>(
        x, W, U, b, W1, b1, W2, b2, perm, rlen, out, B);
}